// Round 2
// baseline (599.138 us; speedup 1.0000x reference)
//
#include <hip/hip_runtime.h>
#include <hip/hip_bf16.h>

typedef __bf16 bf16_t;
typedef __bf16 bfrag __attribute__((ext_vector_type(8)));
typedef float f4 __attribute__((ext_vector_type(4)));

#define S_LEN 2048
#define HQ_N 32
#define HK_N 8
#define D_DIM 64
#define LOG2E 1.4426950408889634f

// ---------------------------------------------------------------------------
// fp32 -> bf16 elementwise convert (x). 8 elems/thread.
// ---------------------------------------------------------------------------
__global__ __launch_bounds__(256) void cvt_bf16(
    const float* __restrict__ src, bf16_t* __restrict__ dst, int n)
{
    int i = (blockIdx.x * 256 + threadIdx.x) * 8;
    if (i >= n) return;
    f4 a = *(const f4*)(src + i);
    f4 b = *(const f4*)(src + i + 4);
    bf16_t o[8];
#pragma unroll
    for (int j = 0; j < 4; ++j) { o[j] = (bf16_t)a[j]; o[4 + j] = (bf16_t)b[j]; }
    *(uint4*)(dst + i) = *(uint4*)o;
}

// ---------------------------------------------------------------------------
// Transpose + cvt: src fp32 [K][N] -> dst bf16 [N][K] (dst rows at row_off).
// 32x32 LDS tiles, block (32,8). Coalesced read and write.
// ---------------------------------------------------------------------------
__global__ __launch_bounds__(256) void transpose_cvt(
    const float* __restrict__ src, bf16_t* __restrict__ dst,
    int K, int N, int row_off)
{
    __shared__ float T[32][33];
    const int n0 = blockIdx.x * 32;
    const int k0 = blockIdx.y * 32;
    const int tx = threadIdx.x;      // 0..31
    const int ty = threadIdx.y;      // 0..7
#pragma unroll
    for (int i = 0; i < 4; ++i)
        T[ty + 8 * i][tx] = src[(size_t)(k0 + ty + 8 * i) * N + n0 + tx];
    __syncthreads();
#pragma unroll
    for (int i = 0; i < 4; ++i)
        dst[(size_t)(row_off + n0 + ty + 8 * i) * K + k0 + tx] =
            (bf16_t)T[tx][ty + 8 * i];
}

// ---------------------------------------------------------------------------
// V transpose pre-pass: qkv bf16 [4096][3072] v-cols -> Vtg[(b*8+hk)*64+d][s].
// Tile 32 s-rows x 64 d-cols per block; block (32,8). Runs after QKV GEMM
// (RoPE does not touch v). 4 MB total, negligible cost.
// ---------------------------------------------------------------------------
__global__ __launch_bounds__(256) void transpose_v(
    const bf16_t* __restrict__ qkv, bf16_t* __restrict__ Vtg)
{
    __shared__ bf16_t T[32][66];     // stride 66 bf16 = 33 dwords: conflict-free cols
    const int s0 = blockIdx.x * 32;
    const int bh = blockIdx.y;       // b*8+hk, 0..15
    const int b  = bh >> 3;
    const int hk = bh & 7;
    const int tx = threadIdx.x;      // 0..31
    const int ty = threadIdx.y;      // 0..7
#pragma unroll
    for (int i = 0; i < 4; ++i) {
        const bf16_t* src = qkv + (size_t)(b * S_LEN + s0 + ty + 8 * i) * 3072 + 2560 + hk * 64;
        T[ty + 8 * i][tx]      = src[tx];
        T[ty + 8 * i][tx + 32] = src[tx + 32];
    }
    __syncthreads();
#pragma unroll
    for (int i = 0; i < 8; ++i) {
        int d = ty + 8 * i;          // 0..63
        Vtg[(size_t)(bh * 64 + d) * S_LEN + s0 + tx] = T[tx][d];
    }
}

// ---------------------------------------------------------------------------
// bf16 GEMM, B pre-transposed: C[M,N] = A[M,K] * Bt[N,K]^T.
// A bf16 [M][K], Bt bf16 [N][K], C bf16 or fp32 (ldc param).
// Block 256 = 4 waves; tile 128x128, BK=64; wave = 64x64 (4x4 of 16x16x32, 2 k-chunks).
// LDS stride 72 (16B-aligned rows, even bank-group spread for b128).
// ---------------------------------------------------------------------------
template<bool OUT_BF16>
__global__ __launch_bounds__(256) void gemm_bt(
    const bf16_t* __restrict__ A, const bf16_t* __restrict__ Bt,
    void* __restrict__ Cv, int M, int N, int K, int ldc)
{
    __shared__ bf16_t As[128][72];
    __shared__ bf16_t Bs[128][72];
    const int tid  = threadIdx.x;
    const int wave = tid >> 6;
    const int lane = tid & 63;
    const int lrow = lane & 15;
    const int quad = lane >> 4;
    const int wm   = (wave >> 1) * 64;
    const int wn   = (wave & 1) * 64;
    const int bm   = blockIdx.y * 128;
    const int bn   = blockIdx.x * 128;

    f4 acc[4][4];
#pragma unroll
    for (int i = 0; i < 4; ++i)
#pragma unroll
        for (int j = 0; j < 4; ++j)
            acc[i][j] = (f4){0.f, 0.f, 0.f, 0.f};

    const int sr = tid >> 2;          // 0..63 staging row
    const int sc = (tid & 3) * 16;    // 0,16,32,48 (k chunk of 16 bf16 = 32B)

    for (int k0 = 0; k0 < K; k0 += 64) {
        uint4 a0 = *(const uint4*)(A  + (size_t)(bm + sr)      * K + k0 + sc);
        uint4 a1 = *(const uint4*)(A  + (size_t)(bm + sr)      * K + k0 + sc + 8);
        uint4 a2 = *(const uint4*)(A  + (size_t)(bm + sr + 64) * K + k0 + sc);
        uint4 a3 = *(const uint4*)(A  + (size_t)(bm + sr + 64) * K + k0 + sc + 8);
        uint4 b0 = *(const uint4*)(Bt + (size_t)(bn + sr)      * K + k0 + sc);
        uint4 b1 = *(const uint4*)(Bt + (size_t)(bn + sr)      * K + k0 + sc + 8);
        uint4 b2 = *(const uint4*)(Bt + (size_t)(bn + sr + 64) * K + k0 + sc);
        uint4 b3 = *(const uint4*)(Bt + (size_t)(bn + sr + 64) * K + k0 + sc + 8);
        __syncthreads();
        *(uint4*)(&As[sr][sc])          = a0;
        *(uint4*)(&As[sr][sc + 8])      = a1;
        *(uint4*)(&As[sr + 64][sc])     = a2;
        *(uint4*)(&As[sr + 64][sc + 8]) = a3;
        *(uint4*)(&Bs[sr][sc])          = b0;
        *(uint4*)(&Bs[sr][sc + 8])      = b1;
        *(uint4*)(&Bs[sr + 64][sc])     = b2;
        *(uint4*)(&Bs[sr + 64][sc + 8]) = b3;
        __syncthreads();

#pragma unroll
        for (int kc = 0; kc < 2; ++kc) {
            bfrag aF[4], bF[4];
#pragma unroll
            for (int i = 0; i < 4; ++i)
                aF[i] = *(const bfrag*)(&As[wm + i * 16 + lrow][kc * 32 + quad * 8]);
#pragma unroll
            for (int j = 0; j < 4; ++j)
                bF[j] = *(const bfrag*)(&Bs[wn + j * 16 + lrow][kc * 32 + quad * 8]);
#pragma unroll
            for (int i = 0; i < 4; ++i)
#pragma unroll
                for (int j = 0; j < 4; ++j)
                    acc[i][j] = __builtin_amdgcn_mfma_f32_16x16x32_bf16(
                        aF[i], bF[j], acc[i][j], 0, 0, 0);
        }
    }

    // C/D layout: col=lane&15, row=(lane>>4)*4+reg
#pragma unroll
    for (int i = 0; i < 4; ++i)
#pragma unroll
        for (int j = 0; j < 4; ++j)
#pragma unroll
            for (int r = 0; r < 4; ++r) {
                int row = bm + wm + i * 16 + quad * 4 + r;
                int col = bn + wn + j * 16 + lrow;
                if (OUT_BF16)
                    ((bf16_t*)Cv)[(size_t)row * ldc + col] = (bf16_t)acc[i][j][r];
                else
                    ((float*)Cv)[(size_t)row * ldc + col] = acc[i][j][r];
            }
}

// ---------------------------------------------------------------------------
// RoPE in-place on fused qkv bf16 [4096][3072]: q = cols h*64+d (h<32),
// k = cols 2048 + hk*64 + d. q additionally scaled by LOG2E (for exp2 softmax).
// One thread per (row, half-dim pair). fp32 math.
// ---------------------------------------------------------------------------
__global__ __launch_bounds__(256) void rope_fused(
    bf16_t* __restrict__ t, const float* __restrict__ cs,
    const float* __restrict__ sn)
{
    int idx = blockIdx.x * 256 + threadIdx.x;   // row-major over [4096][1280]
    int cidx = idx % 1280;
    int row  = idx / 1280;
    int s    = row & (S_LEN - 1);
    int col, d1;
    float scale;
    if (cidx < 1024) {            // q: head h = cidx>>5
        d1 = cidx & 31;
        col = (cidx >> 5) * 64 + d1;
        scale = LOG2E;
    } else {                      // k: head hk = (cidx-1024)>>5
        int c2 = cidx - 1024;
        d1 = c2 & 31;
        col = 2048 + (c2 >> 5) * 64 + d1;
        scale = 1.0f;
    }
    size_t base = (size_t)row * 3072 + col;
    float t1 = (float)t[base];
    float t2 = (float)t[base + 32];
    float c  = cs[s * 32 + d1];
    float s_ = sn[s * 32 + d1];
    t[base]      = (bf16_t)((t1 * c - t2 * s_) * scale);
    t[base + 32] = (bf16_t)((t2 * c + t1 * s_) * scale);
}

// ---------------------------------------------------------------------------
// MFMA flash attention, LDS-free K/V: K fragments loaded directly from qkv
// (row-major matches A-frag); V fragments from pre-transposed Vtg. K tile
// (8 KB) and V tile (8 KB) are L1-resident and shared by the block's 4 waves.
// Only P round-trips through LDS (wave-private rows -> NO barriers at all).
//
// no-max softmax (safe: scores << 88/LOG2E); q pre-scaled by LOG2E so
// p = exp2(s + mask*LOG2E). l accumulated via PV MFMA against a ones B-frag.
//
// QK^T swapped: sc[m][n] = mfma(kf[n], qf[m]) -> thread holds
// S[q = wrow+m*16+lrow][key = n*16+quad*4+r]: mask = 8 b128 loads,
// P-write = 8 ds_write_b64 (contiguous 4 keys).
// ---------------------------------------------------------------------------
__global__ __launch_bounds__(256) void attn_mfma(
    const bf16_t* __restrict__ qkv, const bf16_t* __restrict__ Vtg,
    const float* __restrict__ mask, bf16_t* __restrict__ o)
{
    __shared__ bf16_t Ps[128][72];   // [row][key], wave-private bands

    const int tid  = threadIdx.x;
    const int wave = tid >> 6;
    const int lane = tid & 63;
    const int lrow = lane & 15;
    const int quad = lane >> 4;
    const int qt   = blockIdx.x;     // 0..15
    const int h    = blockIdx.y;     // 0..31
    const int b    = blockIdx.z;     // 0..1
    const int hk   = h >> 2;
    const int s0   = qt * 128;
    const int wrow = wave * 32;

    // ones B-fragment: B[n][k] = (n==0) -> frag[j] = (lrow==0)
    bfrag vOnes;
#pragma unroll
    for (int j = 0; j < 8; ++j) vOnes[j] = (lrow == 0) ? (bf16_t)1.0f : (bf16_t)0.0f;

    // Q fragments (bf16 direct, already *LOG2E)
    bfrag qf[2][2];
#pragma unroll
    for (int m = 0; m < 2; ++m) {
        const bf16_t* qsrc = qkv + (size_t)(b * S_LEN + s0 + wrow + m * 16 + lrow) * 3072 + h * 64;
#pragma unroll
        for (int c = 0; c < 2; ++c)
            qf[m][c] = *(const bfrag*)(qsrc + c * 32 + quad * 8);
    }

    // mask row bases (swapped layout: q = s0 + wrow + m*16 + lrow)
    const float* mrow[2];
#pragma unroll
    for (int m = 0; m < 2; ++m)
        mrow[m] = mask + (size_t)(s0 + wrow + m * 16 + lrow) * S_LEN + quad * 4;

    // K fragment base: row (kt*64 + n*16 + lrow), col quad*8 + c*32
    const bf16_t* kbase = qkv + (size_t)(b * S_LEN + lrow) * 3072 + 2048 + hk * 64 + quad * 8;
    // V fragment base: Vtg row (n*16 + lrow) of head block, col kt*64 + quad*8 + c*32
    const bf16_t* vbase = Vtg + (size_t)((b * 8 + hk) * 64 + lrow) * S_LEN + quad * 8;

    f4 oacc[2][4], lacc[2];
#pragma unroll
    for (int m = 0; m < 2; ++m) {
        lacc[m] = (f4){0.f, 0.f, 0.f, 0.f};
#pragma unroll
        for (int n = 0; n < 4; ++n) oacc[m][n] = (f4){0.f, 0.f, 0.f, 0.f};
    }

    for (int kt = 0; kt < 32; ++kt) {
        // ---- K fragments direct from global (L1-resident, shared by waves) ----
        bfrag kf[4][2];
#pragma unroll
        for (int n = 0; n < 4; ++n) {
            const bf16_t* kp = kbase + (size_t)(kt * 64 + n * 16) * 3072;
            kf[n][0] = *(const bfrag*)(kp);
            kf[n][1] = *(const bfrag*)(kp + 32);
        }
        // ---- V fragments direct from Vtg ----
        bfrag vf[4][2];
#pragma unroll
        for (int n = 0; n < 4; ++n) {
            const bf16_t* vp = vbase + (size_t)(n * 16) * S_LEN + kt * 64;
            vf[n][0] = *(const bfrag*)(vp);
            vf[n][1] = *(const bfrag*)(vp + 32);
        }
        // ---- mask: 4 consecutive keys per b128 ----
        f4 mk[2][4];
#pragma unroll
        for (int m = 0; m < 2; ++m)
#pragma unroll
            for (int n = 0; n < 4; ++n)
                mk[m][n] = *(const f4*)(mrow[m] + kt * 64 + n * 16);

        // ---- S^T tiles: sc[m][n] = mfma(K rows, Q rows) ----
        f4 sc[2][4];
#pragma unroll
        for (int m = 0; m < 2; ++m)
#pragma unroll
            for (int n = 0; n < 4; ++n) {
                f4 a = (f4){0.f, 0.f, 0.f, 0.f};
                a = __builtin_amdgcn_mfma_f32_16x16x32_bf16(kf[n][0], qf[m][0], a, 0, 0, 0);
                a = __builtin_amdgcn_mfma_f32_16x16x32_bf16(kf[n][1], qf[m][1], a, 0, 0, 0);
                sc[m][n] = a;
            }

        // ---- p = exp2(s + mask*LOG2E); write P band: 4 contiguous bf16 ----
#pragma unroll
        for (int m = 0; m < 2; ++m)
#pragma unroll
            for (int n = 0; n < 4; ++n) {
                bf16_t p4[4];
#pragma unroll
                for (int r = 0; r < 4; ++r)
                    p4[r] = (bf16_t)exp2f(fmaf(mk[m][n][r], LOG2E, sc[m][n][r]));
                *(uint2*)(&Ps[wrow + m * 16 + lrow][n * 16 + quad * 4]) = *(uint2*)p4;
            }
        // wave-private rows: compiler lgkmcnt ordering suffices, no barrier

        // ---- O += P V ; l += P 1 ----
        bfrag pf[2][2];
#pragma unroll
        for (int m = 0; m < 2; ++m)
#pragma unroll
            for (int c = 0; c < 2; ++c)
                pf[m][c] = *(const bfrag*)(&Ps[wrow + m * 16 + lrow][c * 32 + quad * 8]);
#pragma unroll
        for (int m = 0; m < 2; ++m) {
#pragma unroll
            for (int n = 0; n < 4; ++n) {
                oacc[m][n] = __builtin_amdgcn_mfma_f32_16x16x32_bf16(pf[m][0], vf[n][0], oacc[m][n], 0, 0, 0);
                oacc[m][n] = __builtin_amdgcn_mfma_f32_16x16x32_bf16(pf[m][1], vf[n][1], oacc[m][n], 0, 0, 0);
            }
            lacc[m] = __builtin_amdgcn_mfma_f32_16x16x32_bf16(pf[m][0], vOnes, lacc[m], 0, 0, 0);
            lacc[m] = __builtin_amdgcn_mfma_f32_16x16x32_bf16(pf[m][1], vOnes, lacc[m], 0, 0, 0);
        }
    }

    // ---- epilogue: broadcast l (col 0 -> lane lrow==0 of each quad), write o ----
#pragma unroll
    for (int m = 0; m < 2; ++m)
#pragma unroll
        for (int r = 0; r < 4; ++r) {
            float lv = __shfl(lacc[m][r], lane & 48, 64);
            float inv = 1.f / lv;
            int row = b * S_LEN + s0 + wrow + m * 16 + quad * 4 + r;
#pragma unroll
            for (int n = 0; n < 4; ++n)
                o[(size_t)row * 2048 + h * 64 + n * 16 + lrow] = (bf16_t)(oacc[m][n][r] * inv);
        }
}

// ---------------------------------------------------------------------------
extern "C" void kernel_launch(void* const* d_in, const int* in_sizes, int n_in,
                              void* d_out, int out_size, void* d_ws, size_t ws_size,
                              hipStream_t stream)
{
    const float* x    = (const float*)d_in[0];
    const float* rc   = (const float*)d_in[1];
    const float* rs   = (const float*)d_in[2];
    const float* mask = (const float*)d_in[3];
    const float* Wq   = (const float*)d_in[4];
    const float* Wk   = (const float*)d_in[5];
    const float* Wv   = (const float*)d_in[6];
    const float* Wo   = (const float*)d_in[7];
    float* out = (float*)d_out;

    char* ws = (char*)d_ws;
    bf16_t* qkv = (bf16_t*)(ws);                  // [4096][3072] = 24 MiB
    bf16_t* xb  = (bf16_t*)(ws + (24u << 20));    // [4096][2048] = 16 MiB
    bf16_t* ob  = xb;                             // aliases xb (dead after QKV GEMM)
    bf16_t* Wt3 = (bf16_t*)(ws + (40u << 20));    // [3072][2048] = 12 MiB
    bf16_t* Vtg = (bf16_t*)(ws + (40u << 20));    // [16*64][2048] = 4 MiB, aliases Wt3 (dead after QKV GEMM)
    bf16_t* Wot = (bf16_t*)(ws + (52u << 20));    // [2048][2048] =  8 MiB

    const int M = 2 * S_LEN;  // 4096
    dim3 blk(256);

    // pre-pass: cvt x, transpose+cvt weights (Wq/Wk/Wv fused into Wt3)
    cvt_bf16<<<(M * 2048) / (256 * 8), blk, 0, stream>>>(x, xb, M * 2048);
    transpose_cvt<<<dim3(64, 64), dim3(32, 8), 0, stream>>>(Wq, Wt3, 2048, 2048, 0);
    transpose_cvt<<<dim3(16, 64), dim3(32, 8), 0, stream>>>(Wk, Wt3, 2048,  512, 2048);
    transpose_cvt<<<dim3(16, 64), dim3(32, 8), 0, stream>>>(Wv, Wt3, 2048,  512, 2560);
    transpose_cvt<<<dim3(64, 64), dim3(32, 8), 0, stream>>>(Wo, Wot, 2048, 2048, 0);

    // fused QKV projection: qkv[4096][3072] bf16
    gemm_bt<true><<<dim3(3072 / 128, M / 128), blk, 0, stream>>>(
        xb, Wt3, qkv, M, 3072, 2048, 3072);

    // RoPE on q (scaled by LOG2E) and k, in place (v untouched)
    rope_fused<<<(M * 1280) / 256, blk, 0, stream>>>(qkv, rc, rs);

    // V transpose for direct fragment loads (Wt3 dead now; Vtg aliases it)
    transpose_v<<<dim3(64, 16), dim3(32, 8), 0, stream>>>(qkv, Vtg);

    // attention -> ob[4096][2048] bf16
    attn_mfma<<<dim3(16, 32, 2), blk, 0, stream>>>(qkv, Vtg, mask, ob);

    // out-projection -> fp32
    gemm_bt<false><<<dim3(2048 / 128, M / 128), blk, 0, stream>>>(
        ob, Wot, out, M, 2048, 2048, 2048);
}

// Round 3
// 463.511 us; speedup vs baseline: 1.2926x; 1.2926x over previous
//
#include <hip/hip_runtime.h>
#include <hip/hip_bf16.h>

typedef __bf16 bf16_t;
typedef __bf16 bfrag __attribute__((ext_vector_type(8)));
typedef float f4 __attribute__((ext_vector_type(4)));

#define S_LEN 2048
#define HQ_N 32
#define HK_N 8
#define D_DIM 64
#define LOG2E 1.4426950408889634f

// async global->LDS, 16B per lane. LDS dest must be wave-uniform base + lane*16.
#define GLOAD16(gp, lp)                                                        \
    __builtin_amdgcn_global_load_lds(                                          \
        (const __attribute__((address_space(1))) void*)(gp),                   \
        (__attribute__((address_space(3))) void*)(lp), 16, 0, 0)

// ---------------------------------------------------------------------------
// fp32 -> bf16 elementwise convert (x). 8 elems/thread.
// ---------------------------------------------------------------------------
__global__ __launch_bounds__(256) void cvt_bf16(
    const float* __restrict__ src, bf16_t* __restrict__ dst, int n)
{
    int i = (blockIdx.x * 256 + threadIdx.x) * 8;
    if (i >= n) return;
    f4 a = *(const f4*)(src + i);
    f4 b = *(const f4*)(src + i + 4);
    bf16_t o[8];
#pragma unroll
    for (int j = 0; j < 4; ++j) { o[j] = (bf16_t)a[j]; o[4 + j] = (bf16_t)b[j]; }
    *(uint4*)(dst + i) = *(uint4*)o;
}

// ---------------------------------------------------------------------------
// Transpose + cvt: src fp32 [K][N] -> dst bf16 [N][K] (dst rows at row_off).
// 32x32 LDS tiles, block (32,8). Coalesced read and write.
// ---------------------------------------------------------------------------
__global__ __launch_bounds__(256) void transpose_cvt(
    const float* __restrict__ src, bf16_t* __restrict__ dst,
    int K, int N, int row_off)
{
    __shared__ float T[32][33];
    const int n0 = blockIdx.x * 32;
    const int k0 = blockIdx.y * 32;
    const int tx = threadIdx.x;      // 0..31
    const int ty = threadIdx.y;      // 0..7
#pragma unroll
    for (int i = 0; i < 4; ++i)
        T[ty + 8 * i][tx] = src[(size_t)(k0 + ty + 8 * i) * N + n0 + tx];
    __syncthreads();
#pragma unroll
    for (int i = 0; i < 4; ++i)
        dst[(size_t)(row_off + n0 + ty + 8 * i) * K + k0 + tx] =
            (bf16_t)T[tx][ty + 8 * i];
}

// ---------------------------------------------------------------------------
// bf16 GEMM, B pre-transposed: C[M,N] = A[M,K] * Bt[N,K]^T.
// m97 structure: linear LDS [128][64], global_load_lds width-16 staging
// (dest = wave-uniform base + lane*16; per-lane global source), 2 barriers
// per K-step. Block 256 = 4 waves; tile 128x128, BK=64; wave = 64x64
// (4x4 of 16x16x32, 2 k-chunks).
// ---------------------------------------------------------------------------
template<bool OUT_BF16>
__global__ __launch_bounds__(256) void gemm_bt(
    const bf16_t* __restrict__ A, const bf16_t* __restrict__ Bt,
    void* __restrict__ Cv, int M, int N, int K, int ldc)
{
    __shared__ bf16_t As[128][64];
    __shared__ bf16_t Bs[128][64];
    const int tid  = threadIdx.x;
    const int wave = tid >> 6;
    const int lane = tid & 63;
    const int lrow = lane & 15;
    const int quad = lane >> 4;
    const int wm   = (wave >> 1) * 64;
    const int wn   = (wave & 1) * 64;
    const int bm   = blockIdx.y * 128;
    const int bn   = blockIdx.x * 128;

    f4 acc[4][4];
#pragma unroll
    for (int i = 0; i < 4; ++i)
#pragma unroll
        for (int j = 0; j < 4; ++j)
            acc[i][j] = (f4){0.f, 0.f, 0.f, 0.f};

    // staging map: thread tid covers LDS bytes [tid*16, tid*16+16) of each
    // 32-row chunk -> row = chunk*32 + tid/8, col = (tid%8)*8.
    const int srow = tid >> 3;        // 0..31
    const int scol = (tid & 7) * 8;   // 0,8,..,56

    for (int k0 = 0; k0 < K; k0 += 64) {
        __syncthreads();   // prior iteration's fragment reads complete
#pragma unroll
        for (int j = 0; j < 4; ++j)
            GLOAD16(A  + (size_t)(bm + j * 32 + srow) * K + k0 + scol,
                    &As[j * 32 + srow][scol]);
#pragma unroll
        for (int j = 0; j < 4; ++j)
            GLOAD16(Bt + (size_t)(bn + j * 32 + srow) * K + k0 + scol,
                    &Bs[j * 32 + srow][scol]);
        __syncthreads();   // compiler inserts vmcnt(0) before barrier

#pragma unroll
        for (int kc = 0; kc < 2; ++kc) {
            bfrag aF[4], bF[4];
#pragma unroll
            for (int i = 0; i < 4; ++i)
                aF[i] = *(const bfrag*)(&As[wm + i * 16 + lrow][kc * 32 + quad * 8]);
#pragma unroll
            for (int j = 0; j < 4; ++j)
                bF[j] = *(const bfrag*)(&Bs[wn + j * 16 + lrow][kc * 32 + quad * 8]);
#pragma unroll
            for (int i = 0; i < 4; ++i)
#pragma unroll
                for (int j = 0; j < 4; ++j)
                    acc[i][j] = __builtin_amdgcn_mfma_f32_16x16x32_bf16(
                        aF[i], bF[j], acc[i][j], 0, 0, 0);
        }
    }

    // C/D layout: col=lane&15, row=(lane>>4)*4+reg
#pragma unroll
    for (int i = 0; i < 4; ++i)
#pragma unroll
        for (int j = 0; j < 4; ++j)
#pragma unroll
            for (int r = 0; r < 4; ++r) {
                int row = bm + wm + i * 16 + quad * 4 + r;
                int col = bn + wn + j * 16 + lrow;
                if (OUT_BF16)
                    ((bf16_t*)Cv)[(size_t)row * ldc + col] = (bf16_t)acc[i][j][r];
                else
                    ((float*)Cv)[(size_t)row * ldc + col] = acc[i][j][r];
            }
}

// ---------------------------------------------------------------------------
// RoPE in-place on fused qkv bf16 [4096][3072]: q = cols h*64+d (h<32),
// k = cols 2048 + hk*64 + d. q additionally scaled by LOG2E (for exp2 softmax).
// One thread per (row, half-dim pair). fp32 math.
// ---------------------------------------------------------------------------
__global__ __launch_bounds__(256) void rope_fused(
    bf16_t* __restrict__ t, const float* __restrict__ cs,
    const float* __restrict__ sn)
{
    int idx = blockIdx.x * 256 + threadIdx.x;   // row-major over [4096][1280]
    int cidx = idx % 1280;
    int row  = idx / 1280;
    int s    = row & (S_LEN - 1);
    int col, d1;
    float scale;
    if (cidx < 1024) {            // q: head h = cidx>>5
        d1 = cidx & 31;
        col = (cidx >> 5) * 64 + d1;
        scale = LOG2E;
    } else {                      // k: head hk = (cidx-1024)>>5
        int c2 = cidx - 1024;
        d1 = c2 & 31;
        col = 2048 + (c2 >> 5) * 64 + d1;
        scale = 1.0f;
    }
    size_t base = (size_t)row * 3072 + col;
    float t1 = (float)t[base];
    float t2 = (float)t[base + 32];
    float c  = cs[s * 32 + d1];
    float s_ = sn[s * 32 + d1];
    t[base]      = (bf16_t)((t1 * c - t2 * s_) * scale);
    t[base + 32] = (bf16_t)((t2 * c + t1 * s_) * scale);
}

// ---------------------------------------------------------------------------
// MFMA flash attention, no-max softmax (safe: scores << 88/LOG2E; bf16/fp32
// share exponent range). q pre-scaled by LOG2E -> p = exp2(s + m*LOG2E).
// l accumulated via extra PV MFMA against a register-built ones B-fragment.
// qkv fused bf16 [4096][3072]; out ob bf16 [4096][2048] (col = h*64+d).
// Block 256 = 4 waves; Q-tile 128 rows (wave = 32); K-tiles of 64 keys.
// (round-0 best-measured version, 196 us)
// ---------------------------------------------------------------------------
__global__ __launch_bounds__(256) void attn_mfma(
    const bf16_t* __restrict__ qkv, const float* __restrict__ mask,
    bf16_t* __restrict__ o)
{
    __shared__ bf16_t Ks[64][72];    // [key][d]
    __shared__ bf16_t Vt[64][72];    // [d][key]
    __shared__ bf16_t Ps[128][72];   // [row][key], wave-private bands

    const int tid  = threadIdx.x;
    const int wave = tid >> 6;
    const int lane = tid & 63;
    const int lrow = lane & 15;
    const int quad = lane >> 4;
    const int qt   = blockIdx.x;     // 0..15
    const int h    = blockIdx.y;     // 0..31
    const int b    = blockIdx.z;     // 0..1
    const int hk   = h >> 2;
    const int s0   = qt * 128;
    const int wrow = wave * 32;

    // ones B-fragment: B[n][k] = (n==0) -> frag[j] = (lrow==0)
    bfrag vOnes;
#pragma unroll
    for (int j = 0; j < 8; ++j) vOnes[j] = (lrow == 0) ? (bf16_t)1.0f : (bf16_t)0.0f;

    // Q fragments (bf16 direct, already *LOG2E)
    bfrag qf[2][2];
#pragma unroll
    for (int m = 0; m < 2; ++m) {
        const bf16_t* qsrc = qkv + (size_t)(b * S_LEN + s0 + wrow + m * 16 + lrow) * 3072 + h * 64;
#pragma unroll
        for (int c = 0; c < 2; ++c)
            qf[m][c] = *(const bfrag*)(qsrc + c * 32 + quad * 8);
    }

    f4 oacc[2][4], lacc[2];
#pragma unroll
    for (int m = 0; m < 2; ++m) {
        lacc[m] = (f4){0.f, 0.f, 0.f, 0.f};
#pragma unroll
        for (int n = 0; n < 4; ++n) oacc[m][n] = (f4){0.f, 0.f, 0.f, 0.f};
    }

    const int skey = tid >> 2;        // K staging: key 0..63
    const int sdc  = (tid & 3) * 16;  // d chunk
    const int vg   = tid >> 5;        // V staging: key octet 0..7
    const int vp   = tid & 31;        // d pair 0..31

    for (int kt = 0; kt < 32; ++kt) {
        // ---- global prefetch ----
        const bf16_t* ksrc = qkv + (size_t)(b * S_LEN + kt * 64 + skey) * 3072 + 2048 + hk * 64 + sdc;
        uint4 k0 = *(const uint4*)(ksrc);
        uint4 k1 = *(const uint4*)(ksrc + 8);
        unsigned int vw[8];
#pragma unroll
        for (int kk = 0; kk < 8; ++kk)
            vw[kk] = *(const unsigned int*)(qkv + (size_t)(b * S_LEN + kt * 64 + vg * 8 + kk) * 3072
                                            + 2560 + hk * 64 + 2 * vp);
        __syncthreads();   // prior iteration's LDS reads complete
        *(uint4*)(&Ks[skey][sdc])     = k0;
        *(uint4*)(&Ks[skey][sdc + 8]) = k1;
        {   // V transpose: lane holds 8 keys x 2 dims -> 2 b128 row-writes
            unsigned short lo[8], hi[8];
#pragma unroll
            for (int kk = 0; kk < 8; ++kk) { lo[kk] = vw[kk] & 0xffff; hi[kk] = vw[kk] >> 16; }
            *(uint4*)(&Vt[2 * vp][vg * 8])     = *(uint4*)lo;
            *(uint4*)(&Vt[2 * vp + 1][vg * 8]) = *(uint4*)hi;
        }
        __syncthreads();

        // ---- mask prefetch (scalar; L2/L3-resident) ----
        float mk[2][4][4];
#pragma unroll
        for (int m = 0; m < 2; ++m)
#pragma unroll
            for (int n = 0; n < 4; ++n)
#pragma unroll
                for (int r = 0; r < 4; ++r)
                    mk[m][n][r] = mask[(size_t)(s0 + wrow + m * 16 + quad * 4 + r) * S_LEN
                                       + kt * 64 + n * 16 + lrow];

        // ---- S = Q K^T (already *LOG2E) ----
        bfrag kf[4][2];
#pragma unroll
        for (int n = 0; n < 4; ++n)
#pragma unroll
            for (int c = 0; c < 2; ++c)
                kf[n][c] = *(const bfrag*)(&Ks[n * 16 + lrow][c * 32 + quad * 8]);

        f4 sc[2][4];
#pragma unroll
        for (int m = 0; m < 2; ++m)
#pragma unroll
            for (int n = 0; n < 4; ++n) {
                f4 a = (f4){0.f, 0.f, 0.f, 0.f};
                a = __builtin_amdgcn_mfma_f32_16x16x32_bf16(qf[m][0], kf[n][0], a, 0, 0, 0);
                a = __builtin_amdgcn_mfma_f32_16x16x32_bf16(qf[m][1], kf[n][1], a, 0, 0, 0);
                sc[m][n] = a;
            }

        // ---- p = exp2(s + mask*LOG2E); write P (bf16, wave-private rows) ----
#pragma unroll
        for (int m = 0; m < 2; ++m)
#pragma unroll
            for (int n = 0; n < 4; ++n)
#pragma unroll
                for (int r = 0; r < 4; ++r) {
                    float p = exp2f(fmaf(mk[m][n][r], LOG2E, sc[m][n][r]));
                    Ps[wrow + m * 16 + quad * 4 + r][n * 16 + lrow] = (bf16_t)p;
                }
        // wave-private rows: compiler lgkmcnt ordering suffices, no barrier

        // ---- O += P V ; l += P 1 ----
        bfrag pf[2][2], vf[4][2];
#pragma unroll
        for (int m = 0; m < 2; ++m)
#pragma unroll
            for (int c = 0; c < 2; ++c)
                pf[m][c] = *(const bfrag*)(&Ps[wrow + m * 16 + lrow][c * 32 + quad * 8]);
#pragma unroll
        for (int n = 0; n < 4; ++n)
#pragma unroll
            for (int c = 0; c < 2; ++c)
                vf[n][c] = *(const bfrag*)(&Vt[n * 16 + lrow][c * 32 + quad * 8]);
#pragma unroll
        for (int m = 0; m < 2; ++m) {
#pragma unroll
            for (int n = 0; n < 4; ++n) {
                oacc[m][n] = __builtin_amdgcn_mfma_f32_16x16x32_bf16(pf[m][0], vf[n][0], oacc[m][n], 0, 0, 0);
                oacc[m][n] = __builtin_amdgcn_mfma_f32_16x16x32_bf16(pf[m][1], vf[n][1], oacc[m][n], 0, 0, 0);
            }
            lacc[m] = __builtin_amdgcn_mfma_f32_16x16x32_bf16(pf[m][0], vOnes, lacc[m], 0, 0, 0);
            lacc[m] = __builtin_amdgcn_mfma_f32_16x16x32_bf16(pf[m][1], vOnes, lacc[m], 0, 0, 0);
        }
    }

    // ---- epilogue: broadcast l (col 0 -> lane lrow==0 of each quad), write o ----
#pragma unroll
    for (int m = 0; m < 2; ++m)
#pragma unroll
        for (int r = 0; r < 4; ++r) {
            float lv = __shfl(lacc[m][r], lane & 48, 64);
            float inv = 1.f / lv;
            int row = b * S_LEN + s0 + wrow + m * 16 + quad * 4 + r;
#pragma unroll
            for (int n = 0; n < 4; ++n)
                o[(size_t)row * 2048 + h * 64 + n * 16 + lrow] = (bf16_t)(oacc[m][n][r] * inv);
        }
}

// ---------------------------------------------------------------------------
extern "C" void kernel_launch(void* const* d_in, const int* in_sizes, int n_in,
                              void* d_out, int out_size, void* d_ws, size_t ws_size,
                              hipStream_t stream)
{
    const float* x    = (const float*)d_in[0];
    const float* rc   = (const float*)d_in[1];
    const float* rs   = (const float*)d_in[2];
    const float* mask = (const float*)d_in[3];
    const float* Wq   = (const float*)d_in[4];
    const float* Wk   = (const float*)d_in[5];
    const float* Wv   = (const float*)d_in[6];
    const float* Wo   = (const float*)d_in[7];
    float* out = (float*)d_out;

    char* ws = (char*)d_ws;
    bf16_t* qkv = (bf16_t*)(ws);                  // [4096][3072] = 24 MiB
    bf16_t* xb  = (bf16_t*)(ws + (24u << 20));    // [4096][2048] = 16 MiB
    bf16_t* ob  = xb;                             // aliases xb (dead after QKV GEMM)
    bf16_t* Wt3 = (bf16_t*)(ws + (40u << 20));    // [3072][2048] = 12 MiB
    bf16_t* Wot = (bf16_t*)(ws + (52u << 20));    // [2048][2048] =  8 MiB

    const int M = 2 * S_LEN;  // 4096
    dim3 blk(256);

    // pre-pass: cvt x, transpose+cvt weights (Wq/Wk/Wv fused into Wt3)
    cvt_bf16<<<(M * 2048) / (256 * 8), blk, 0, stream>>>(x, xb, M * 2048);
    transpose_cvt<<<dim3(64, 64), dim3(32, 8), 0, stream>>>(Wq, Wt3, 2048, 2048, 0);
    transpose_cvt<<<dim3(16, 64), dim3(32, 8), 0, stream>>>(Wk, Wt3, 2048,  512, 2048);
    transpose_cvt<<<dim3(16, 64), dim3(32, 8), 0, stream>>>(Wv, Wt3, 2048,  512, 2560);
    transpose_cvt<<<dim3(64, 64), dim3(32, 8), 0, stream>>>(Wo, Wot, 2048, 2048, 0);

    // fused QKV projection: qkv[4096][3072] bf16
    gemm_bt<true><<<dim3(3072 / 128, M / 128), blk, 0, stream>>>(
        xb, Wt3, qkv, M, 3072, 2048, 3072);

    // RoPE on q (scaled by LOG2E) and k, in place
    rope_fused<<<(M * 1280) / 256, blk, 0, stream>>>(qkv, rc, rs);

    // attention -> ob[4096][2048] bf16
    attn_mfma<<<dim3(16, 32, 2), blk, 0, stream>>>(qkv, mask, ob);

    // out-projection -> fp32
    gemm_bt<false><<<dim3(2048 / 128, M / 128), blk, 0, stream>>>(
        ob, Wot, out, M, 2048, 2048, 2048);
}

// Round 4
// 435.846 us; speedup vs baseline: 1.3747x; 1.0635x over previous
//
#include <hip/hip_runtime.h>
#include <hip/hip_bf16.h>

typedef __bf16 bf16_t;
typedef __bf16 bfrag __attribute__((ext_vector_type(8)));
typedef __bf16 b4 __attribute__((ext_vector_type(4)));
typedef float f4 __attribute__((ext_vector_type(4)));

#define S_LEN 2048
#define HQ_N 32
#define HK_N 8
#define D_DIM 64
#define LOG2E 1.4426950408889634f

// ---------------------------------------------------------------------------
// fp32 -> bf16 elementwise convert (x). 8 elems/thread.
// ---------------------------------------------------------------------------
__global__ __launch_bounds__(256) void cvt_bf16(
    const float* __restrict__ src, bf16_t* __restrict__ dst, int n)
{
    int i = (blockIdx.x * 256 + threadIdx.x) * 8;
    if (i >= n) return;
    f4 a = *(const f4*)(src + i);
    f4 b = *(const f4*)(src + i + 4);
    bf16_t o[8];
#pragma unroll
    for (int j = 0; j < 4; ++j) { o[j] = (bf16_t)a[j]; o[4 + j] = (bf16_t)b[j]; }
    *(uint4*)(dst + i) = *(uint4*)o;
}

// ---------------------------------------------------------------------------
// Transpose + cvt + scale: src fp32 [K][N] -> dst bf16 [N][K] (rows at
// row_off), dst = src^T * scale. 32x32 LDS tiles, block (32,8). Coalesced.
// Used for weights (scale=1) and for the attention mask (scale=LOG2E).
// ---------------------------------------------------------------------------
__global__ __launch_bounds__(256) void transpose_cvt(
    const float* __restrict__ src, bf16_t* __restrict__ dst,
    int K, int N, int row_off, float scale)
{
    __shared__ float T[32][33];
    const int n0 = blockIdx.x * 32;
    const int k0 = blockIdx.y * 32;
    const int tx = threadIdx.x;      // 0..31
    const int ty = threadIdx.y;      // 0..7
#pragma unroll
    for (int i = 0; i < 4; ++i)
        T[ty + 8 * i][tx] = src[(size_t)(k0 + ty + 8 * i) * N + n0 + tx];
    __syncthreads();
#pragma unroll
    for (int i = 0; i < 4; ++i)
        dst[(size_t)(row_off + n0 + ty + 8 * i) * K + k0 + tx] =
            (bf16_t)(T[tx][ty + 8 * i] * scale);
}

// ---------------------------------------------------------------------------
// V transpose pre-pass: qkv bf16 [4096][3072] v-cols -> Vtg[(b*8+hk)*64+d][s].
// Tile 32 s-rows x 64 d-cols per block; block (32,8). (validated in R1)
// ---------------------------------------------------------------------------
__global__ __launch_bounds__(256) void transpose_v(
    const bf16_t* __restrict__ qkv, bf16_t* __restrict__ Vtg)
{
    __shared__ bf16_t T[32][66];     // stride 66 bf16 = 33 dwords: conflict-free cols
    const int s0 = blockIdx.x * 32;
    const int bh = blockIdx.y;       // b*8+hk, 0..15
    const int b  = bh >> 3;
    const int hk = bh & 7;
    const int tx = threadIdx.x;      // 0..31
    const int ty = threadIdx.y;      // 0..7
#pragma unroll
    for (int i = 0; i < 4; ++i) {
        const bf16_t* src = qkv + (size_t)(b * S_LEN + s0 + ty + 8 * i) * 3072 + 2560 + hk * 64;
        T[ty + 8 * i][tx]      = src[tx];
        T[ty + 8 * i][tx + 32] = src[tx + 32];
    }
    __syncthreads();
#pragma unroll
    for (int i = 0; i < 8; ++i) {
        int d = ty + 8 * i;          // 0..63
        Vtg[(size_t)(bh * 64 + d) * S_LEN + s0 + tx] = T[tx][d];
    }
}

// ---------------------------------------------------------------------------
// bf16 GEMM, B pre-transposed: C[M,N] = A[M,K] * Bt[N,K]^T.
// (round-0 best-measured version: reg staging, LDS stride 72)
// Block 256 = 4 waves; tile 128x128, BK=64; wave = 64x64 (4x4 of 16x16x32).
// ---------------------------------------------------------------------------
template<bool OUT_BF16>
__global__ __launch_bounds__(256) void gemm_bt(
    const bf16_t* __restrict__ A, const bf16_t* __restrict__ Bt,
    void* __restrict__ Cv, int M, int N, int K, int ldc)
{
    __shared__ bf16_t As[128][72];
    __shared__ bf16_t Bs[128][72];
    const int tid  = threadIdx.x;
    const int wave = tid >> 6;
    const int lane = tid & 63;
    const int lrow = lane & 15;
    const int quad = lane >> 4;
    const int wm   = (wave >> 1) * 64;
    const int wn   = (wave & 1) * 64;
    const int bm   = blockIdx.y * 128;
    const int bn   = blockIdx.x * 128;

    f4 acc[4][4];
#pragma unroll
    for (int i = 0; i < 4; ++i)
#pragma unroll
        for (int j = 0; j < 4; ++j)
            acc[i][j] = (f4){0.f, 0.f, 0.f, 0.f};

    const int sr = tid >> 2;          // 0..63 staging row
    const int sc = (tid & 3) * 16;    // 0,16,32,48 (k chunk of 16 bf16 = 32B)

    for (int k0 = 0; k0 < K; k0 += 64) {
        uint4 a0 = *(const uint4*)(A  + (size_t)(bm + sr)      * K + k0 + sc);
        uint4 a1 = *(const uint4*)(A  + (size_t)(bm + sr)      * K + k0 + sc + 8);
        uint4 a2 = *(const uint4*)(A  + (size_t)(bm + sr + 64) * K + k0 + sc);
        uint4 a3 = *(const uint4*)(A  + (size_t)(bm + sr + 64) * K + k0 + sc + 8);
        uint4 b0 = *(const uint4*)(Bt + (size_t)(bn + sr)      * K + k0 + sc);
        uint4 b1 = *(const uint4*)(Bt + (size_t)(bn + sr)      * K + k0 + sc + 8);
        uint4 b2 = *(const uint4*)(Bt + (size_t)(bn + sr + 64) * K + k0 + sc);
        uint4 b3 = *(const uint4*)(Bt + (size_t)(bn + sr + 64) * K + k0 + sc + 8);
        __syncthreads();
        *(uint4*)(&As[sr][sc])          = a0;
        *(uint4*)(&As[sr][sc + 8])      = a1;
        *(uint4*)(&As[sr + 64][sc])     = a2;
        *(uint4*)(&As[sr + 64][sc + 8]) = a3;
        *(uint4*)(&Bs[sr][sc])          = b0;
        *(uint4*)(&Bs[sr][sc + 8])      = b1;
        *(uint4*)(&Bs[sr + 64][sc])     = b2;
        *(uint4*)(&Bs[sr + 64][sc + 8]) = b3;
        __syncthreads();

#pragma unroll
        for (int kc = 0; kc < 2; ++kc) {
            bfrag aF[4], bF[4];
#pragma unroll
            for (int i = 0; i < 4; ++i)
                aF[i] = *(const bfrag*)(&As[wm + i * 16 + lrow][kc * 32 + quad * 8]);
#pragma unroll
            for (int j = 0; j < 4; ++j)
                bF[j] = *(const bfrag*)(&Bs[wn + j * 16 + lrow][kc * 32 + quad * 8]);
#pragma unroll
            for (int i = 0; i < 4; ++i)
#pragma unroll
                for (int j = 0; j < 4; ++j)
                    acc[i][j] = __builtin_amdgcn_mfma_f32_16x16x32_bf16(
                        aF[i], bF[j], acc[i][j], 0, 0, 0);
        }
    }

    // C/D layout: col=lane&15, row=(lane>>4)*4+reg
#pragma unroll
    for (int i = 0; i < 4; ++i)
#pragma unroll
        for (int j = 0; j < 4; ++j)
#pragma unroll
            for (int r = 0; r < 4; ++r) {
                int row = bm + wm + i * 16 + quad * 4 + r;
                int col = bn + wn + j * 16 + lrow;
                if (OUT_BF16)
                    ((bf16_t*)Cv)[(size_t)row * ldc + col] = (bf16_t)acc[i][j][r];
                else
                    ((float*)Cv)[(size_t)row * ldc + col] = acc[i][j][r];
            }
}

// ---------------------------------------------------------------------------
// RoPE in-place on fused qkv bf16 [4096][3072]: q = cols h*64+d (h<32),
// k = cols 2048 + hk*64 + d. q additionally scaled by LOG2E (for exp2 softmax).
// ---------------------------------------------------------------------------
__global__ __launch_bounds__(256) void rope_fused(
    bf16_t* __restrict__ t, const float* __restrict__ cs,
    const float* __restrict__ sn)
{
    int idx = blockIdx.x * 256 + threadIdx.x;   // row-major over [4096][1280]
    int cidx = idx % 1280;
    int row  = idx / 1280;
    int s    = row & (S_LEN - 1);
    int col, d1;
    float scale;
    if (cidx < 1024) {            // q: head h = cidx>>5
        d1 = cidx & 31;
        col = (cidx >> 5) * 64 + d1;
        scale = LOG2E;
    } else {                      // k: head hk = (cidx-1024)>>5
        int c2 = cidx - 1024;
        d1 = c2 & 31;
        col = 2048 + (c2 >> 5) * 64 + d1;
        scale = 1.0f;
    }
    size_t base = (size_t)row * 3072 + col;
    float t1 = (float)t[base];
    float t2 = (float)t[base + 32];
    float c  = cs[s * 32 + d1];
    float s_ = sn[s * 32 + d1];
    t[base]      = (bf16_t)((t1 * c - t2 * s_) * scale);
    t[base + 32] = (bf16_t)((t2 * c + t1 * s_) * scale);
}

// ---------------------------------------------------------------------------
// MFMA flash attention, no-max softmax (safe: scores << 88/LOG2E).
// q pre-scaled by LOG2E; mask pre-transposed+pre-scaled (maskT bf16 [k][q],
// value = mask*LOG2E) and folded into the QK accumulator INIT -> the 32
// scalar mask loads + fmaf of R0 become 8 b64 loads + cvt.
// V pre-transposed to Vtg[d][s] -> in-loop repack deleted; Vt staged with
// 2 b128 loads + 2 stride-72 LDS writes (same shape as K staging).
// Everything else identical to the 197us round-0 version.
// ---------------------------------------------------------------------------
__global__ __launch_bounds__(256) void attn_mfma(
    const bf16_t* __restrict__ qkv, const bf16_t* __restrict__ Vtg,
    const bf16_t* __restrict__ maskT, bf16_t* __restrict__ o)
{
    __shared__ bf16_t Ks[64][72];    // [key][d]
    __shared__ bf16_t Vt[64][72];    // [d][key]
    __shared__ bf16_t Ps[128][72];   // [row][key], wave-private bands

    const int tid  = threadIdx.x;
    const int wave = tid >> 6;
    const int lane = tid & 63;
    const int lrow = lane & 15;
    const int quad = lane >> 4;
    const int qt   = blockIdx.x;     // 0..15
    const int h    = blockIdx.y;     // 0..31
    const int b    = blockIdx.z;     // 0..1
    const int hk   = h >> 2;
    const int s0   = qt * 128;
    const int wrow = wave * 32;

    // ones B-fragment: B[n][k] = (n==0) -> frag[j] = (lrow==0)
    bfrag vOnes;
#pragma unroll
    for (int j = 0; j < 8; ++j) vOnes[j] = (lrow == 0) ? (bf16_t)1.0f : (bf16_t)0.0f;

    // Q fragments (bf16 direct, already *LOG2E)
    bfrag qf[2][2];
#pragma unroll
    for (int m = 0; m < 2; ++m) {
        const bf16_t* qsrc = qkv + (size_t)(b * S_LEN + s0 + wrow + m * 16 + lrow) * 3072 + h * 64;
#pragma unroll
        for (int c = 0; c < 2; ++c)
            qf[m][c] = *(const bfrag*)(qsrc + c * 32 + quad * 8);
    }

    // maskT bases: maskT[k][q], k = kt*64 + n*16 + lrow, q = s0+wrow+m*16+quad*4+r
    const bf16_t* mbase[2];
#pragma unroll
    for (int m = 0; m < 2; ++m)
        mbase[m] = maskT + (size_t)lrow * S_LEN + s0 + wrow + m * 16 + quad * 4;

    f4 oacc[2][4], lacc[2];
#pragma unroll
    for (int m = 0; m < 2; ++m) {
        lacc[m] = (f4){0.f, 0.f, 0.f, 0.f};
#pragma unroll
        for (int n = 0; n < 4; ++n) oacc[m][n] = (f4){0.f, 0.f, 0.f, 0.f};
    }

    const int skey = tid >> 2;        // staging row: K key / V dim, 0..63
    const int sdc  = (tid & 3) * 16;  // 16-elem chunk
    const bf16_t* vsrc0 = Vtg + (size_t)((b * 8 + hk) * 64 + skey) * S_LEN + sdc;

    for (int kt = 0; kt < 32; ++kt) {
        // ---- global prefetch (K from qkv rows; V from pre-transposed Vtg) ----
        const bf16_t* ksrc = qkv + (size_t)(b * S_LEN + kt * 64 + skey) * 3072 + 2048 + hk * 64 + sdc;
        uint4 k0 = *(const uint4*)(ksrc);
        uint4 k1 = *(const uint4*)(ksrc + 8);
        const bf16_t* vsrc = vsrc0 + kt * 64;
        uint4 v0 = *(const uint4*)(vsrc);
        uint4 v1 = *(const uint4*)(vsrc + 8);
        __syncthreads();   // prior iteration's LDS reads complete
        *(uint4*)(&Ks[skey][sdc])     = k0;
        *(uint4*)(&Ks[skey][sdc + 8]) = k1;
        *(uint4*)(&Vt[skey][sdc])     = v0;
        *(uint4*)(&Vt[skey][sdc + 8]) = v1;
        __syncthreads();

        // ---- S = Q K^T + mask (mask in accumulator init, already *LOG2E) ----
        bfrag kf[4][2];
#pragma unroll
        for (int n = 0; n < 4; ++n)
#pragma unroll
            for (int c = 0; c < 2; ++c)
                kf[n][c] = *(const bfrag*)(&Ks[n * 16 + lrow][c * 32 + quad * 8]);

        f4 sc[2][4];
#pragma unroll
        for (int m = 0; m < 2; ++m)
#pragma unroll
            for (int n = 0; n < 4; ++n) {
                b4 mv = *(const b4*)(mbase[m] + (size_t)(kt * 64 + n * 16) * S_LEN);
                f4 a = (f4){(float)mv[0], (float)mv[1], (float)mv[2], (float)mv[3]};
                a = __builtin_amdgcn_mfma_f32_16x16x32_bf16(qf[m][0], kf[n][0], a, 0, 0, 0);
                a = __builtin_amdgcn_mfma_f32_16x16x32_bf16(qf[m][1], kf[n][1], a, 0, 0, 0);
                sc[m][n] = a;
            }

        // ---- p = exp2(s); write P (bf16, wave-private rows) ----
#pragma unroll
        for (int m = 0; m < 2; ++m)
#pragma unroll
            for (int n = 0; n < 4; ++n)
#pragma unroll
                for (int r = 0; r < 4; ++r) {
                    float p = exp2f(sc[m][n][r]);
                    Ps[wrow + m * 16 + quad * 4 + r][n * 16 + lrow] = (bf16_t)p;
                }
        // wave-private rows: compiler lgkmcnt ordering suffices, no barrier

        // ---- O += P V ; l += P 1 ----
        bfrag pf[2][2], vf[4][2];
#pragma unroll
        for (int m = 0; m < 2; ++m)
#pragma unroll
            for (int c = 0; c < 2; ++c)
                pf[m][c] = *(const bfrag*)(&Ps[wrow + m * 16 + lrow][c * 32 + quad * 8]);
#pragma unroll
        for (int n = 0; n < 4; ++n)
#pragma unroll
            for (int c = 0; c < 2; ++c)
                vf[n][c] = *(const bfrag*)(&Vt[n * 16 + lrow][c * 32 + quad * 8]);
#pragma unroll
        for (int m = 0; m < 2; ++m) {
#pragma unroll
            for (int n = 0; n < 4; ++n) {
                oacc[m][n] = __builtin_amdgcn_mfma_f32_16x16x32_bf16(pf[m][0], vf[n][0], oacc[m][n], 0, 0, 0);
                oacc[m][n] = __builtin_amdgcn_mfma_f32_16x16x32_bf16(pf[m][1], vf[n][1], oacc[m][n], 0, 0, 0);
            }
            lacc[m] = __builtin_amdgcn_mfma_f32_16x16x32_bf16(pf[m][0], vOnes, lacc[m], 0, 0, 0);
            lacc[m] = __builtin_amdgcn_mfma_f32_16x16x32_bf16(pf[m][1], vOnes, lacc[m], 0, 0, 0);
        }
    }

    // ---- epilogue: broadcast l (col 0 -> lane lrow==0 of each quad), write o ----
#pragma unroll
    for (int m = 0; m < 2; ++m)
#pragma unroll
        for (int r = 0; r < 4; ++r) {
            float lv = __shfl(lacc[m][r], lane & 48, 64);
            float inv = 1.f / lv;
            int row = b * S_LEN + s0 + wrow + m * 16 + quad * 4 + r;
#pragma unroll
            for (int n = 0; n < 4; ++n)
                o[(size_t)row * 2048 + h * 64 + n * 16 + lrow] = (bf16_t)(oacc[m][n][r] * inv);
        }
}

// ---------------------------------------------------------------------------
extern "C" void kernel_launch(void* const* d_in, const int* in_sizes, int n_in,
                              void* d_out, int out_size, void* d_ws, size_t ws_size,
                              hipStream_t stream)
{
    const float* x    = (const float*)d_in[0];
    const float* rc   = (const float*)d_in[1];
    const float* rs   = (const float*)d_in[2];
    const float* mask = (const float*)d_in[3];
    const float* Wq   = (const float*)d_in[4];
    const float* Wk   = (const float*)d_in[5];
    const float* Wv   = (const float*)d_in[6];
    const float* Wo   = (const float*)d_in[7];
    float* out = (float*)d_out;

    char* ws = (char*)d_ws;
    bf16_t* qkv   = (bf16_t*)(ws);                  // [4096][3072] = 24 MiB
    bf16_t* xb    = (bf16_t*)(ws + (24u << 20));    // [4096][2048] = 16 MiB
    bf16_t* ob    = xb;                             // aliases xb (dead after QKV GEMM)
    bf16_t* Wt3   = (bf16_t*)(ws + (40u << 20));    // [3072][2048] = 12 MiB (dead after QKV GEMM)
    bf16_t* maskT = (bf16_t*)(ws + (40u << 20));    // [2048][2048] =  8 MiB, aliases Wt3
    bf16_t* Vtg   = (bf16_t*)(ws + (48u << 20));    // [16*64][2048] = 4 MiB, aliases Wt3 tail
    bf16_t* Wot   = (bf16_t*)(ws + (52u << 20));    // [2048][2048] =  8 MiB

    const int M = 2 * S_LEN;  // 4096
    dim3 blk(256);

    // pre-pass: cvt x, transpose+cvt weights (Wq/Wk/Wv fused into Wt3)
    cvt_bf16<<<(M * 2048) / (256 * 8), blk, 0, stream>>>(x, xb, M * 2048);
    transpose_cvt<<<dim3(64, 64), dim3(32, 8), 0, stream>>>(Wq, Wt3, 2048, 2048, 0, 1.0f);
    transpose_cvt<<<dim3(16, 64), dim3(32, 8), 0, stream>>>(Wk, Wt3, 2048,  512, 2048, 1.0f);
    transpose_cvt<<<dim3(16, 64), dim3(32, 8), 0, stream>>>(Wv, Wt3, 2048,  512, 2560, 1.0f);
    transpose_cvt<<<dim3(64, 64), dim3(32, 8), 0, stream>>>(Wo, Wot, 2048, 2048, 0, 1.0f);

    // fused QKV projection: qkv[4096][3072] bf16
    gemm_bt<true><<<dim3(3072 / 128, M / 128), blk, 0, stream>>>(
        xb, Wt3, qkv, M, 3072, 2048, 3072);

    // RoPE on q (scaled by LOG2E) and k, in place (v untouched)
    rope_fused<<<(M * 1280) / 256, blk, 0, stream>>>(qkv, rc, rs);

    // Wt3 dead now: build maskT (mask^T * LOG2E, bf16) and Vtg over it
    transpose_cvt<<<dim3(64, 64), dim3(32, 8), 0, stream>>>(
        mask, maskT, S_LEN, S_LEN, 0, LOG2E);
    transpose_v<<<dim3(64, 16), dim3(32, 8), 0, stream>>>(qkv, Vtg);

    // attention -> ob[4096][2048] bf16
    attn_mfma<<<dim3(16, 32, 2), blk, 0, stream>>>(qkv, Vtg, maskT, ob);

    // out-projection -> fp32
    gemm_bt<false><<<dim3(2048 / 128, M / 128), blk, 0, stream>>>(
        ob, Wot, out, M, 2048, 2048, 2048);
}

// Round 5
// 429.094 us; speedup vs baseline: 1.3963x; 1.0157x over previous
//
#include <hip/hip_runtime.h>
#include <hip/hip_bf16.h>

typedef __bf16 bf16_t;
typedef __bf16 bfrag __attribute__((ext_vector_type(8)));
typedef __bf16 b4 __attribute__((ext_vector_type(4)));
typedef float f4 __attribute__((ext_vector_type(4)));

#define S_LEN 2048
#define HQ_N 32
#define HK_N 8
#define D_DIM 64
#define LOG2E 1.4426950408889634f

// ---------------------------------------------------------------------------
// fp32 -> bf16 elementwise convert (x). 8 elems/thread.
// ---------------------------------------------------------------------------
__global__ __launch_bounds__(256) void cvt_bf16(
    const float* __restrict__ src, bf16_t* __restrict__ dst, int n)
{
    int i = (blockIdx.x * 256 + threadIdx.x) * 8;
    if (i >= n) return;
    f4 a = *(const f4*)(src + i);
    f4 b = *(const f4*)(src + i + 4);
    bf16_t o[8];
#pragma unroll
    for (int j = 0; j < 4; ++j) { o[j] = (bf16_t)a[j]; o[4 + j] = (bf16_t)b[j]; }
    *(uint4*)(dst + i) = *(uint4*)o;
}

// ---------------------------------------------------------------------------
// Transpose + cvt + scale: src fp32 [K][N] -> dst bf16 [N][K] (rows at
// row_off), dst = src^T * scale. 32x32 LDS tiles, block (32,8). Coalesced.
// Used for weights (scale=1) and for the attention mask (scale=LOG2E).
// ---------------------------------------------------------------------------
__global__ __launch_bounds__(256) void transpose_cvt(
    const float* __restrict__ src, bf16_t* __restrict__ dst,
    int K, int N, int row_off, float scale)
{
    __shared__ float T[32][33];
    const int n0 = blockIdx.x * 32;
    const int k0 = blockIdx.y * 32;
    const int tx = threadIdx.x;      // 0..31
    const int ty = threadIdx.y;      // 0..7
#pragma unroll
    for (int i = 0; i < 4; ++i)
        T[ty + 8 * i][tx] = src[(size_t)(k0 + ty + 8 * i) * N + n0 + tx];
    __syncthreads();
#pragma unroll
    for (int i = 0; i < 4; ++i)
        dst[(size_t)(row_off + n0 + ty + 8 * i) * K + k0 + tx] =
            (bf16_t)(T[tx][ty + 8 * i] * scale);
}

// ---------------------------------------------------------------------------
// V transpose pre-pass: qkv bf16 [4096][3072] v-cols -> Vtg[(b*8+hk)*64+d][s].
// Tile 32 s-rows x 64 d-cols per block; block (32,8). (validated in R1)
// ---------------------------------------------------------------------------
__global__ __launch_bounds__(256) void transpose_v(
    const bf16_t* __restrict__ qkv, bf16_t* __restrict__ Vtg)
{
    __shared__ bf16_t T[32][66];     // stride 66 bf16 = 33 dwords: conflict-free cols
    const int s0 = blockIdx.x * 32;
    const int bh = blockIdx.y;       // b*8+hk, 0..15
    const int b  = bh >> 3;
    const int hk = bh & 7;
    const int tx = threadIdx.x;      // 0..31
    const int ty = threadIdx.y;      // 0..7
#pragma unroll
    for (int i = 0; i < 4; ++i) {
        const bf16_t* src = qkv + (size_t)(b * S_LEN + s0 + ty + 8 * i) * 3072 + 2560 + hk * 64;
        T[ty + 8 * i][tx]      = src[tx];
        T[ty + 8 * i][tx + 32] = src[tx + 32];
    }
    __syncthreads();
#pragma unroll
    for (int i = 0; i < 8; ++i) {
        int d = ty + 8 * i;          // 0..63
        Vtg[(size_t)(bh * 64 + d) * S_LEN + s0 + tx] = T[tx][d];
    }
}

// ---------------------------------------------------------------------------
// bf16 GEMM, B pre-transposed: C[M,N] = A[M,K] * Bt[N,K]^T.
// R0 structure (reg staging, LDS stride 72) + software pipeline: loads for
// tile k+1 are issued BEFORE the MFMA block of tile k, so global latency
// hides under compute instead of being exposed between the two barriers.
// Block 256 = 4 waves; tile 128x128, BK=64; wave = 64x64 (4x4 of 16x16x32).
// ---------------------------------------------------------------------------
template<bool OUT_BF16>
__global__ __launch_bounds__(256) void gemm_bt(
    const bf16_t* __restrict__ A, const bf16_t* __restrict__ Bt,
    void* __restrict__ Cv, int M, int N, int K, int ldc)
{
    __shared__ bf16_t As[128][72];
    __shared__ bf16_t Bs[128][72];
    const int tid  = threadIdx.x;
    const int wave = tid >> 6;
    const int lane = tid & 63;
    const int lrow = lane & 15;
    const int quad = lane >> 4;
    const int wm   = (wave >> 1) * 64;
    const int wn   = (wave & 1) * 64;
    const int bm   = blockIdx.y * 128;
    const int bn   = blockIdx.x * 128;

    f4 acc[4][4];
#pragma unroll
    for (int i = 0; i < 4; ++i)
#pragma unroll
        for (int j = 0; j < 4; ++j)
            acc[i][j] = (f4){0.f, 0.f, 0.f, 0.f};

    const int sr = tid >> 2;          // 0..63 staging row
    const int sc = (tid & 3) * 16;    // 0,16,32,48 (k chunk of 16 bf16 = 32B)

    const bf16_t* Ap0 = A  + (size_t)(bm + sr)      * K + sc;
    const bf16_t* Ap1 = A  + (size_t)(bm + sr + 64) * K + sc;
    const bf16_t* Bp0 = Bt + (size_t)(bn + sr)      * K + sc;
    const bf16_t* Bp1 = Bt + (size_t)(bn + sr + 64) * K + sc;

    // prologue: load tile 0
    uint4 a0 = *(const uint4*)(Ap0);
    uint4 a1 = *(const uint4*)(Ap0 + 8);
    uint4 a2 = *(const uint4*)(Ap1);
    uint4 a3 = *(const uint4*)(Ap1 + 8);
    uint4 b0 = *(const uint4*)(Bp0);
    uint4 b1 = *(const uint4*)(Bp0 + 8);
    uint4 b2 = *(const uint4*)(Bp1);
    uint4 b3 = *(const uint4*)(Bp1 + 8);

    for (int k0 = 0; k0 < K; k0 += 64) {
        __syncthreads();   // prior iteration's fragment reads complete
        *(uint4*)(&As[sr][sc])          = a0;
        *(uint4*)(&As[sr][sc + 8])      = a1;
        *(uint4*)(&As[sr + 64][sc])     = a2;
        *(uint4*)(&As[sr + 64][sc + 8]) = a3;
        *(uint4*)(&Bs[sr][sc])          = b0;
        *(uint4*)(&Bs[sr][sc + 8])      = b1;
        *(uint4*)(&Bs[sr + 64][sc])     = b2;
        *(uint4*)(&Bs[sr + 64][sc + 8]) = b3;
        __syncthreads();

        // issue next-tile loads; latency overlaps the MFMA block below
        if (k0 + 64 < K) {
            int kn = k0 + 64;
            a0 = *(const uint4*)(Ap0 + kn);
            a1 = *(const uint4*)(Ap0 + kn + 8);
            a2 = *(const uint4*)(Ap1 + kn);
            a3 = *(const uint4*)(Ap1 + kn + 8);
            b0 = *(const uint4*)(Bp0 + kn);
            b1 = *(const uint4*)(Bp0 + kn + 8);
            b2 = *(const uint4*)(Bp1 + kn);
            b3 = *(const uint4*)(Bp1 + kn + 8);
        }

#pragma unroll
        for (int kc = 0; kc < 2; ++kc) {
            bfrag aF[4], bF[4];
#pragma unroll
            for (int i = 0; i < 4; ++i)
                aF[i] = *(const bfrag*)(&As[wm + i * 16 + lrow][kc * 32 + quad * 8]);
#pragma unroll
            for (int j = 0; j < 4; ++j)
                bF[j] = *(const bfrag*)(&Bs[wn + j * 16 + lrow][kc * 32 + quad * 8]);
#pragma unroll
            for (int i = 0; i < 4; ++i)
#pragma unroll
                for (int j = 0; j < 4; ++j)
                    acc[i][j] = __builtin_amdgcn_mfma_f32_16x16x32_bf16(
                        aF[i], bF[j], acc[i][j], 0, 0, 0);
        }
    }

    // C/D layout: col=lane&15, row=(lane>>4)*4+reg
#pragma unroll
    for (int i = 0; i < 4; ++i)
#pragma unroll
        for (int j = 0; j < 4; ++j)
#pragma unroll
            for (int r = 0; r < 4; ++r) {
                int row = bm + wm + i * 16 + quad * 4 + r;
                int col = bn + wn + j * 16 + lrow;
                if (OUT_BF16)
                    ((bf16_t*)Cv)[(size_t)row * ldc + col] = (bf16_t)acc[i][j][r];
                else
                    ((float*)Cv)[(size_t)row * ldc + col] = acc[i][j][r];
            }
}

// ---------------------------------------------------------------------------
// RoPE in-place on fused qkv bf16 [4096][3072]: q = cols h*64+d (h<32),
// k = cols 2048 + hk*64 + d. q additionally scaled by LOG2E (for exp2 softmax).
// ---------------------------------------------------------------------------
__global__ __launch_bounds__(256) void rope_fused(
    bf16_t* __restrict__ t, const float* __restrict__ cs,
    const float* __restrict__ sn)
{
    int idx = blockIdx.x * 256 + threadIdx.x;   // row-major over [4096][1280]
    int cidx = idx % 1280;
    int row  = idx / 1280;
    int s    = row & (S_LEN - 1);
    int col, d1;
    float scale;
    if (cidx < 1024) {            // q: head h = cidx>>5
        d1 = cidx & 31;
        col = (cidx >> 5) * 64 + d1;
        scale = LOG2E;
    } else {                      // k: head hk = (cidx-1024)>>5
        int c2 = cidx - 1024;
        d1 = c2 & 31;
        col = 2048 + (c2 >> 5) * 64 + d1;
        scale = 1.0f;
    }
    size_t base = (size_t)row * 3072 + col;
    float t1 = (float)t[base];
    float t2 = (float)t[base + 32];
    float c  = cs[s * 32 + d1];
    float s_ = sn[s * 32 + d1];
    t[base]      = (bf16_t)((t1 * c - t2 * s_) * scale);
    t[base + 32] = (bf16_t)((t2 * c + t1 * s_) * scale);
}

// ---------------------------------------------------------------------------
// MFMA flash attention, no-max softmax (safe: scores << 88/LOG2E).
// q pre-scaled by LOG2E; mask pre-transposed+pre-scaled (maskT bf16 [k][q],
// value = mask*LOG2E) folded into the QK accumulator init. V pre-transposed
// to Vtg[d][s]; Vt staged with 2 b128 loads + 2 stride-72 LDS writes.
// (best-measured version, 186 us)
// ---------------------------------------------------------------------------
__global__ __launch_bounds__(256) void attn_mfma(
    const bf16_t* __restrict__ qkv, const bf16_t* __restrict__ Vtg,
    const bf16_t* __restrict__ maskT, bf16_t* __restrict__ o)
{
    __shared__ bf16_t Ks[64][72];    // [key][d]
    __shared__ bf16_t Vt[64][72];    // [d][key]
    __shared__ bf16_t Ps[128][72];   // [row][key], wave-private bands

    const int tid  = threadIdx.x;
    const int wave = tid >> 6;
    const int lane = tid & 63;
    const int lrow = lane & 15;
    const int quad = lane >> 4;
    const int qt   = blockIdx.x;     // 0..15
    const int h    = blockIdx.y;     // 0..31
    const int b    = blockIdx.z;     // 0..1
    const int hk   = h >> 2;
    const int s0   = qt * 128;
    const int wrow = wave * 32;

    // ones B-fragment: B[n][k] = (n==0) -> frag[j] = (lrow==0)
    bfrag vOnes;
#pragma unroll
    for (int j = 0; j < 8; ++j) vOnes[j] = (lrow == 0) ? (bf16_t)1.0f : (bf16_t)0.0f;

    // Q fragments (bf16 direct, already *LOG2E)
    bfrag qf[2][2];
#pragma unroll
    for (int m = 0; m < 2; ++m) {
        const bf16_t* qsrc = qkv + (size_t)(b * S_LEN + s0 + wrow + m * 16 + lrow) * 3072 + h * 64;
#pragma unroll
        for (int c = 0; c < 2; ++c)
            qf[m][c] = *(const bfrag*)(qsrc + c * 32 + quad * 8);
    }

    // maskT bases: maskT[k][q], k = kt*64 + n*16 + lrow, q = s0+wrow+m*16+quad*4+r
    const bf16_t* mbase[2];
#pragma unroll
    for (int m = 0; m < 2; ++m)
        mbase[m] = maskT + (size_t)lrow * S_LEN + s0 + wrow + m * 16 + quad * 4;

    f4 oacc[2][4], lacc[2];
#pragma unroll
    for (int m = 0; m < 2; ++m) {
        lacc[m] = (f4){0.f, 0.f, 0.f, 0.f};
#pragma unroll
        for (int n = 0; n < 4; ++n) oacc[m][n] = (f4){0.f, 0.f, 0.f, 0.f};
    }

    const int skey = tid >> 2;        // staging row: K key / V dim, 0..63
    const int sdc  = (tid & 3) * 16;  // 16-elem chunk
    const bf16_t* vsrc0 = Vtg + (size_t)((b * 8 + hk) * 64 + skey) * S_LEN + sdc;

    for (int kt = 0; kt < 32; ++kt) {
        // ---- global prefetch (K from qkv rows; V from pre-transposed Vtg) ----
        const bf16_t* ksrc = qkv + (size_t)(b * S_LEN + kt * 64 + skey) * 3072 + 2048 + hk * 64 + sdc;
        uint4 k0 = *(const uint4*)(ksrc);
        uint4 k1 = *(const uint4*)(ksrc + 8);
        const bf16_t* vsrc = vsrc0 + kt * 64;
        uint4 v0 = *(const uint4*)(vsrc);
        uint4 v1 = *(const uint4*)(vsrc + 8);
        __syncthreads();   // prior iteration's LDS reads complete
        *(uint4*)(&Ks[skey][sdc])     = k0;
        *(uint4*)(&Ks[skey][sdc + 8]) = k1;
        *(uint4*)(&Vt[skey][sdc])     = v0;
        *(uint4*)(&Vt[skey][sdc + 8]) = v1;
        __syncthreads();

        // ---- S = Q K^T + mask (mask in accumulator init, already *LOG2E) ----
        bfrag kf[4][2];
#pragma unroll
        for (int n = 0; n < 4; ++n)
#pragma unroll
            for (int c = 0; c < 2; ++c)
                kf[n][c] = *(const bfrag*)(&Ks[n * 16 + lrow][c * 32 + quad * 8]);

        f4 sc[2][4];
#pragma unroll
        for (int m = 0; m < 2; ++m)
#pragma unroll
            for (int n = 0; n < 4; ++n) {
                b4 mv = *(const b4*)(mbase[m] + (size_t)(kt * 64 + n * 16) * S_LEN);
                f4 a = (f4){(float)mv[0], (float)mv[1], (float)mv[2], (float)mv[3]};
                a = __builtin_amdgcn_mfma_f32_16x16x32_bf16(qf[m][0], kf[n][0], a, 0, 0, 0);
                a = __builtin_amdgcn_mfma_f32_16x16x32_bf16(qf[m][1], kf[n][1], a, 0, 0, 0);
                sc[m][n] = a;
            }

        // ---- p = exp2(s); write P (bf16, wave-private rows) ----
#pragma unroll
        for (int m = 0; m < 2; ++m)
#pragma unroll
            for (int n = 0; n < 4; ++n)
#pragma unroll
                for (int r = 0; r < 4; ++r) {
                    float p = exp2f(sc[m][n][r]);
                    Ps[wrow + m * 16 + quad * 4 + r][n * 16 + lrow] = (bf16_t)p;
                }
        // wave-private rows: compiler lgkmcnt ordering suffices, no barrier

        // ---- O += P V ; l += P 1 ----
        bfrag pf[2][2], vf[4][2];
#pragma unroll
        for (int m = 0; m < 2; ++m)
#pragma unroll
            for (int c = 0; c < 2; ++c)
                pf[m][c] = *(const bfrag*)(&Ps[wrow + m * 16 + lrow][c * 32 + quad * 8]);
#pragma unroll
        for (int n = 0; n < 4; ++n)
#pragma unroll
            for (int c = 0; c < 2; ++c)
                vf[n][c] = *(const bfrag*)(&Vt[n * 16 + lrow][c * 32 + quad * 8]);
#pragma unroll
        for (int m = 0; m < 2; ++m) {
#pragma unroll
            for (int n = 0; n < 4; ++n) {
                oacc[m][n] = __builtin_amdgcn_mfma_f32_16x16x32_bf16(pf[m][0], vf[n][0], oacc[m][n], 0, 0, 0);
                oacc[m][n] = __builtin_amdgcn_mfma_f32_16x16x32_bf16(pf[m][1], vf[n][1], oacc[m][n], 0, 0, 0);
            }
            lacc[m] = __builtin_amdgcn_mfma_f32_16x16x32_bf16(pf[m][0], vOnes, lacc[m], 0, 0, 0);
            lacc[m] = __builtin_amdgcn_mfma_f32_16x16x32_bf16(pf[m][1], vOnes, lacc[m], 0, 0, 0);
        }
    }

    // ---- epilogue: broadcast l (col 0 -> lane lrow==0 of each quad), write o ----
#pragma unroll
    for (int m = 0; m < 2; ++m)
#pragma unroll
        for (int r = 0; r < 4; ++r) {
            float lv = __shfl(lacc[m][r], lane & 48, 64);
            float inv = 1.f / lv;
            int row = b * S_LEN + s0 + wrow + m * 16 + quad * 4 + r;
#pragma unroll
            for (int n = 0; n < 4; ++n)
                o[(size_t)row * 2048 + h * 64 + n * 16 + lrow] = (bf16_t)(oacc[m][n][r] * inv);
        }
}

// ---------------------------------------------------------------------------
extern "C" void kernel_launch(void* const* d_in, const int* in_sizes, int n_in,
                              void* d_out, int out_size, void* d_ws, size_t ws_size,
                              hipStream_t stream)
{
    const float* x    = (const float*)d_in[0];
    const float* rc   = (const float*)d_in[1];
    const float* rs   = (const float*)d_in[2];
    const float* mask = (const float*)d_in[3];
    const float* Wq   = (const float*)d_in[4];
    const float* Wk   = (const float*)d_in[5];
    const float* Wv   = (const float*)d_in[6];
    const float* Wo   = (const float*)d_in[7];
    float* out = (float*)d_out;

    char* ws = (char*)d_ws;
    bf16_t* qkv   = (bf16_t*)(ws);                  // [4096][3072] = 24 MiB
    bf16_t* xb    = (bf16_t*)(ws + (24u << 20));    // [4096][2048] = 16 MiB
    bf16_t* ob    = xb;                             // aliases xb (dead after QKV GEMM)
    bf16_t* Wt3   = (bf16_t*)(ws + (40u << 20));    // [3072][2048] = 12 MiB (dead after QKV GEMM)
    bf16_t* maskT = (bf16_t*)(ws + (40u << 20));    // [2048][2048] =  8 MiB, aliases Wt3
    bf16_t* Vtg   = (bf16_t*)(ws + (48u << 20));    // [16*64][2048] = 4 MiB, aliases Wt3 tail
    bf16_t* Wot   = (bf16_t*)(ws + (52u << 20));    // [2048][2048] =  8 MiB

    const int M = 2 * S_LEN;  // 4096
    dim3 blk(256);

    // pre-pass: cvt x, transpose+cvt weights (Wq/Wk/Wv fused into Wt3)
    cvt_bf16<<<(M * 2048) / (256 * 8), blk, 0, stream>>>(x, xb, M * 2048);
    transpose_cvt<<<dim3(64, 64), dim3(32, 8), 0, stream>>>(Wq, Wt3, 2048, 2048, 0, 1.0f);
    transpose_cvt<<<dim3(16, 64), dim3(32, 8), 0, stream>>>(Wk, Wt3, 2048,  512, 2048, 1.0f);
    transpose_cvt<<<dim3(16, 64), dim3(32, 8), 0, stream>>>(Wv, Wt3, 2048,  512, 2560, 1.0f);
    transpose_cvt<<<dim3(64, 64), dim3(32, 8), 0, stream>>>(Wo, Wot, 2048, 2048, 0, 1.0f);

    // fused QKV projection: qkv[4096][3072] bf16
    gemm_bt<true><<<dim3(3072 / 128, M / 128), blk, 0, stream>>>(
        xb, Wt3, qkv, M, 3072, 2048, 3072);

    // RoPE on q (scaled by LOG2E) and k, in place (v untouched)
    rope_fused<<<(M * 1280) / 256, blk, 0, stream>>>(qkv, rc, rs);

    // Wt3 dead now: build maskT (mask^T * LOG2E, bf16) and Vtg over it
    transpose_cvt<<<dim3(64, 64), dim3(32, 8), 0, stream>>>(
        mask, maskT, S_LEN, S_LEN, 0, LOG2E);
    transpose_v<<<dim3(64, 16), dim3(32, 8), 0, stream>>>(qkv, Vtg);

    // attention -> ob[4096][2048] bf16
    attn_mfma<<<dim3(16, 32, 2), blk, 0, stream>>>(qkv, Vtg, maskT, ob);

    // out-projection -> fp32
    gemm_bt<false><<<dim3(2048 / 128, M / 128), blk, 0, stream>>>(
        ob, Wot, out, M, 2048, 2048, 2048);
}